// Round 10
// baseline (2035.972 us; speedup 1.0000x reference)
//
#include <hip/hip_runtime.h>
#include <hip/hip_bf16.h>
#include <math.h>

typedef __hip_bfloat16 bf16;
typedef __attribute__((ext_vector_type(8))) short short8;
typedef __attribute__((ext_vector_type(4))) float float4v;
typedef __attribute__((ext_vector_type(4))) unsigned int uint4n;
union u4s8 { uint4 u; short8 s; };
union pk8 { uint4 u; uint4n un; __hip_bfloat162 h[4]; };

#define GBLK 768
#define GTHR (GBLK*256)

__device__ __forceinline__ float elu_f(float x){ return x > 0.f ? x : expm1f(x); }
__device__ __forceinline__ float loadf(const void* base, size_t idx, int isbf){
    return isbf ? __bfloat162float(((const bf16*)base)[idx]) : ((const float*)base)[idx];
}

// grid barrier: one counter slot per use; all 768 blocks are co-resident by construction
__device__ __forceinline__ void gbar(int* bar){
    __syncthreads();                                   // drains vmem (compiler emits vmcnt(0))
    if (threadIdx.x == 0){
        __threadfence();                               // release: wbl2 to HBM (cross-XCD)
        __hip_atomic_fetch_add(bar, 1, __ATOMIC_RELAXED, __HIP_MEMORY_SCOPE_AGENT);
        long long it = 0;
        while (__hip_atomic_load(bar, __ATOMIC_RELAXED, __HIP_MEMORY_SCOPE_AGENT) < GBLK){
            __builtin_amdgcn_s_sleep(2);
            if (++it > (1LL<<27)) break;               // safety valve: fail finite, never hang
        }
    }
    __syncthreads();
    __threadfence();                                   // acquire: inv L1/L2 (all waves)
}

__global__ __launch_bounds__(256, 3) void mega_kernel(
        const void* __restrict__ x, const int* __restrict__ ei,
        const void* W0, const void* W1, const void* W2, const void* W3,
        const void* B0, const void* B1, const void* B2, const void* B3,
        const void* Wm, const void* bm,
        int* __restrict__ ctl, float* __restrict__ dinv, int* __restrict__ counts,
        int* __restrict__ offsets, int* __restrict__ cursor,
        int* __restrict__ partial, int* __restrict__ blockoff,
        bf16* __restrict__ wt, int* __restrict__ csr, void* __restrict__ xw,
        void* __restrict__ dout, int N, int E)
{
    __shared__ uint4 xs[64*17];          // 17408 B — also aliased as int/float scratch
    int tid = threadIdx.x, bid = blockIdx.x;
    int gid = bid*256 + tid;
    int* raw = ctl;
    int* bar = ctl + 4;

    // ---------- P0: zero counts + dtype detection ----------
    for (int i = gid; i < N; i += GTHR) counts[i] = 0;
    {
        const unsigned* ei_u = (const unsigned*)ei;
        const unsigned* x_u  = (const unsigned*)x;
        int min_xwords = N*128/2;
        int orv = 0;
        if (gid < 16384 && E > 0){
            long long idx = ((long long)gid * (long long)E) / 16384;
            long long w = 2*idx + 1;
            if (w < 2LL*E) orv = (int)ei_u[w];
        }
        int cnt = 0;
        int s = gid - 16384;
        if (s >= 0 && s < 4096){
            long long idx = ((long long)s * min_xwords) / 4096;
            if (idx < min_xwords){
                unsigned e = (x_u[idx] >> 7) & 0xFFu;
                cnt = (e >= 96u && e <= 160u) ? 1 : 0;
            }
        }
        if (bid < 80){                    // only blocks holding samples reduce+atomic
            int* sd = (int*)xs;
            int* sc = sd + 256;
            sd[tid] = orv; sc[tid] = cnt;
            __syncthreads();
            #pragma unroll
            for (int off = 128; off > 0; off >>= 1){
                if (tid < off){ sd[tid] |= sd[tid+off]; sc[tid] += sc[tid+off]; }
                __syncthreads();
            }
            if (tid == 0){
                if (sd[0]) atomicOr(&raw[0], sd[0]);
                if (sc[0]) atomicAdd(&raw[1], sc[0]);
            }
            __syncthreads();
        }
    }
    gbar(&bar[0]);
    int is64 = (raw[0] == 0);
    int isbf = (raw[1]*2 > 4096);

    // ---------- P1: degree histogram + W transpose ----------
    for (int e = gid; e < E; e += GTHR){
        int d = is64 ? ei[2*(E + e)] : ei[E + e];
        if ((unsigned)d < (unsigned)N) atomicAdd(&counts[d], 1);
    }
    if (isbf){
        const bf16* Ws0 = (const bf16*)W0; const bf16* Ws1 = (const bf16*)W1;
        const bf16* Ws2 = (const bf16*)W2; const bf16* Ws3 = (const bf16*)W3;
        for (int j = gid; j < 4*16384; j += GTHR){
            int l = j >> 14, r = j & 16383;
            int n = r >> 7, k = r & 127;
            const bf16* Wl = (l == 0) ? Ws0 : (l == 1) ? Ws1 : (l == 2) ? Ws2 : Ws3;
            wt[j] = Wl[k*128 + n];
        }
    }
    gbar(&bar[1]);

    // ---------- P2: per-chunk totals ----------
    int nb = (N + 255) >> 8;
    {
        int* sd = (int*)xs;
        for (int c = bid; c < nb; c += GBLK){
            int i = c*256 + tid;
            int v = (i < N) ? counts[i] : 0;
            sd[tid] = v;
            __syncthreads();
            #pragma unroll
            for (int off = 1; off < 256; off <<= 1){
                int t = (tid >= off) ? sd[tid-off] : 0;
                __syncthreads();
                sd[tid] += t;
                __syncthreads();
            }
            if (tid == 255) partial[c] = sd[255];
            __syncthreads();
        }
    }
    gbar(&bar[2]);

    // ---------- P3: block 0 exclusive-scans chunk totals ----------
    if (bid == 0){
        int* sd = (int*)xs;
        int* runp = sd + 512;
        if (tid == 0) runp[0] = 0;
        __syncthreads();
        for (int c0 = 0; c0 < nb; c0 += 256){
            int i = c0 + tid;
            int v = (i < nb) ? partial[i] : 0;
            sd[tid] = v;
            __syncthreads();
            #pragma unroll
            for (int off = 1; off < 256; off <<= 1){
                int t = (tid >= off) ? sd[tid-off] : 0;
                __syncthreads();
                sd[tid] += t;
                __syncthreads();
            }
            if (i < nb) blockoff[i] = runp[0] + sd[tid] - v;
            __syncthreads();
            if (tid == 255) runp[0] += sd[255];
            __syncthreads();
        }
    }
    gbar(&bar[3]);

    // ---------- P4: offsets + cursor + dinv ----------
    {
        int* sd = (int*)xs;
        for (int c = bid; c < nb; c += GBLK){
            int i = c*256 + tid;
            int v = (i < N) ? counts[i] : 0;
            sd[tid] = v;
            __syncthreads();
            #pragma unroll
            for (int off = 1; off < 256; off <<= 1){
                int t = (tid >= off) ? sd[tid-off] : 0;
                __syncthreads();
                sd[tid] += t;
                __syncthreads();
            }
            if (i < N){
                int o = blockoff[c] + sd[tid] - v;
                offsets[i] = o;
                cursor[i]  = o;
                double dd = (double)(v + 1);
                if (dd < 1.0) dd = 1.0;
                dinv[i] = (float)(1.0 / sqrt(dd));
            }
            __syncthreads();
        }
    }
    gbar(&bar[4]);

    // ---------- layers: P5 = scatter + gemm0; then agg/gemm alternating ----------
    for (int l = 0; l < 4; ++l){
        if (l == 0){
            for (int e = gid; e < E; e += GTHR){
                int d = is64 ? ei[2*(E + e)] : ei[E + e];
                int s = is64 ? ei[2*e]       : ei[e];
                if ((unsigned)d < (unsigned)N){
                    int pos = atomicAdd(&cursor[d], 1);
                    if ((unsigned)pos < (unsigned)E) csr[pos] = s;
                }
            }
        }
        const void* Xin = (l == 0) ? x : (const void*)dout;
        const void* Wl  = (l == 0) ? W0 : (l == 1) ? W1 : (l == 2) ? W2 : W3;
        const void* Bl  = (l == 0) ? B0 : (l == 1) ? B1 : (l == 2) ? B2 : B3;

        // ----- gemm phase -----
        if (isbf){
            int wave = tid >> 6, lane = tid & 63;
            int quad = lane >> 4, nn = lane & 15;
            const uint4* wt4 = (const uint4*)(wt + (size_t)l*16384);
            for (int t = bid; t*64 < N; t += GBLK){
                int r0 = t*64;
                __syncthreads();
                for (int i = tid; i < 1024; i += 256){
                    int r = i >> 4, c = i & 15;
                    uint4 v = make_uint4(0,0,0,0);
                    if (r0 + r < N) v = ((const uint4*)Xin)[(size_t)(r0 + r)*16 + c];
                    xs[r*17 + c] = v;
                }
                __syncthreads();
                u4s8 a[4];
                #pragma unroll
                for (int ks = 0; ks < 4; ks++) a[ks].u = xs[(wave*16 + nn)*17 + ks*4 + quad];
                float4v acc[8];
                #pragma unroll
                for (int t8 = 0; t8 < 8; t8++) acc[t8] = (float4v){0.f,0.f,0.f,0.f};
                #pragma unroll
                for (int ks = 0; ks < 4; ks++){
                    #pragma unroll
                    for (int t8 = 0; t8 < 8; t8++){
                        u4s8 b; b.u = wt4[(size_t)(16*t8 + nn)*16 + ks*4 + quad];
                        acc[t8] = __builtin_amdgcn_mfma_f32_16x16x32_bf16(a[ks].s, b.s, acc[t8], 0, 0, 0);
                    }
                }
                __syncthreads();
                short* xss = (short*)xs;
                #pragma unroll
                for (int t8 = 0; t8 < 8; t8++){
                    #pragma unroll
                    for (int r = 0; r < 4; r++){
                        union { bf16 h; short s; } cv;
                        cv.h = __float2bfloat16(acc[t8][r]);
                        xss[(wave*16 + quad*4 + r)*136 + 16*t8 + nn] = cv.s;
                    }
                }
                __syncthreads();
                #pragma unroll
                for (int it = 0; it < 4; it++){
                    int idx = it*64 + lane;
                    int r = idx >> 4, c = idx & 15;
                    int grow = r0 + wave*16 + r;
                    if (grow < N) ((uint4*)xw)[(size_t)grow*16 + c] = xs[(wave*16 + r)*17 + c];
                }
            }
        } else {
            float* xsf = (float*)xs;
            const float* Wf = (const float*)Wl;
            for (int t = bid; t*32 < N; t += GBLK){
                int r0 = t*32;
                __syncthreads();
                for (int i = tid; i < 1024; i += 256){
                    int r = i >> 5, k4 = i & 31;
                    float4 v = make_float4(0.f,0.f,0.f,0.f);
                    if (r0 + r < N) v = ((const float4*)Xin)[(size_t)(r0 + r)*32 + k4];
                    *(float4*)&xsf[r*132 + k4*4] = v;
                }
                __syncthreads();
                int cp = tid & 63, rg = tid >> 6;
                float acc0[8], acc1[8];
                #pragma unroll
                for (int i = 0; i < 8; i++){ acc0[i] = 0.f; acc1[i] = 0.f; }
                for (int k0 = 0; k0 < 128; k0 += 4){
                    float wa0 = Wf[(k0+0)*128 + cp], wa1 = Wf[(k0+1)*128 + cp];
                    float wa2 = Wf[(k0+2)*128 + cp], wa3 = Wf[(k0+3)*128 + cp];
                    float wb0 = Wf[(k0+0)*128 + cp + 64], wb1 = Wf[(k0+1)*128 + cp + 64];
                    float wb2 = Wf[(k0+2)*128 + cp + 64], wb3 = Wf[(k0+3)*128 + cp + 64];
                    #pragma unroll
                    for (int rr = 0; rr < 8; rr++){
                        float4 xv = *(const float4*)&xsf[(rg*8 + rr)*132 + k0];
                        acc0[rr] += xv.x*wa0; acc0[rr] += xv.y*wa1; acc0[rr] += xv.z*wa2; acc0[rr] += xv.w*wa3;
                        acc1[rr] += xv.x*wb0; acc1[rr] += xv.y*wb1; acc1[rr] += xv.z*wb2; acc1[rr] += xv.w*wb3;
                    }
                }
                #pragma unroll
                for (int rr = 0; rr < 8; rr++){
                    int r = r0 + rg*8 + rr;
                    if (r < N){
                        ((float*)xw)[(size_t)r*128 + cp]      = acc0[rr];
                        ((float*)xw)[(size_t)r*128 + cp + 64] = acc1[rr];
                    }
                }
            }
        }
        gbar(&bar[5 + 2*l]);

        // ----- agg phase -----
        {
            int wave = tid >> 6, lane = tid & 63;
            int gwave = bid*4 + wave;
            if (isbf){
                const uint4* XB4 = (const uint4*)xw;
                int g = lane >> 4, ll = lane & 15;
                for (int n = gwave; n < N; n += GBLK*4){
                    float dn = dinv[n];
                    float sw = dn*dn;
                    int j0 = offsets[n], cnt = counts[n];
                    float acc[8];
                    #pragma unroll
                    for (int i = 0; i < 8; i++) acc[i] = 0.f;
                    if (g == 0){
                        pk8 u; u.u = XB4[(size_t)n*16 + ll];
                        #pragma unroll
                        for (int i = 0; i < 4; i++){
                            acc[2*i]   += __bfloat162float(u.h[i].x)*sw;
                            acc[2*i+1] += __bfloat162float(u.h[i].y)*sw;
                        }
                    }
                    for (int base = 0; base < cnt; base += 64){
                        int m = cnt - base; if (m > 64) m = 64;
                        int s_l = 0; float w_l = 0.f;
                        if (lane < m){
                            int s = __builtin_nontemporal_load(&csr[j0 + base + lane]);
                            if ((unsigned)s < (unsigned)N){ s_l = s; w_l = dinv[s]*dn; }
                        }
                        for (int j = 0; j + 8 <= m + 7; j += 8){
                            int jj0 = j + g, jj1 = j + 4 + g;
                            int   sA = __shfl(s_l, jj0 & 63), sB = __shfl(s_l, jj1 & 63);
                            float wA = __shfl(w_l, jj0 & 63), wB = __shfl(w_l, jj1 & 63);
                            if (jj0 >= 64){ wA = 0.f; sA = 0; }
                            if (jj1 >= 64){ wB = 0.f; sB = 0; }
                            pk8 uA, uB;
                            uA.u = XB4[(size_t)sA*16 + ll];
                            uB.u = XB4[(size_t)sB*16 + ll];
                            #pragma unroll
                            for (int i = 0; i < 4; i++){
                                acc[2*i]   += __bfloat162float(uA.h[i].x)*wA;
                                acc[2*i+1] += __bfloat162float(uA.h[i].y)*wA;
                            }
                            #pragma unroll
                            for (int i = 0; i < 4; i++){
                                acc[2*i]   += __bfloat162float(uB.h[i].x)*wB;
                                acc[2*i+1] += __bfloat162float(uB.h[i].y)*wB;
                            }
                        }
                    }
                    #pragma unroll
                    for (int i = 0; i < 8; i++){
                        acc[i] += __shfl_xor(acc[i], 16);
                        acc[i] += __shfl_xor(acc[i], 32);
                    }
                    if (g == 0){
                        pk8 o;
                        #pragma unroll
                        for (int i = 0; i < 4; i++){
                            float ax = elu_f(acc[2*i]   + loadf(Bl, 8*ll + 2*i,     1));
                            float ay = elu_f(acc[2*i+1] + loadf(Bl, 8*ll + 2*i + 1, 1));
                            o.h[i].x = __float2bfloat16(ax);
                            o.h[i].y = __float2bfloat16(ay);
                        }
                        __builtin_nontemporal_store(o.un, &((uint4n*)dout)[(size_t)n*16 + ll]);
                    }
                }
            } else {
                const float2* XF = (const float2*)xw;
                for (int n = gwave; n < N; n += GBLK*4){
                    float dn = dinv[n];
                    float sw = dn*dn;
                    int j0 = offsets[n], cnt = counts[n];
                    float2 v = XF[(size_t)n*64 + lane];
                    float accx = v.x*sw, accy = v.y*sw;
                    for (int base = 0; base < cnt; base += 64){
                        int m = cnt - base; if (m > 64) m = 64;
                        int s_l = 0; float w_l = 0.f;
                        if (lane < m){
                            int s = __builtin_nontemporal_load(&csr[j0 + base + lane]);
                            if ((unsigned)s < (unsigned)N){ s_l = s; w_l = dinv[s]*dn; }
                        }
                        int j = 0;
                        for (; j + 4 <= m; j += 4){
                            int   s0 = __shfl(s_l, j),   s1 = __shfl(s_l, j+1), s2 = __shfl(s_l, j+2), s3 = __shfl(s_l, j+3);
                            float w0 = __shfl(w_l, j),   w1 = __shfl(w_l, j+1), w2 = __shfl(w_l, j+2), w3 = __shfl(w_l, j+3);
                            float2 u0 = XF[(size_t)s0*64 + lane];
                            float2 u1 = XF[(size_t)s1*64 + lane];
                            float2 u2 = XF[(size_t)s2*64 + lane];
                            float2 u3 = XF[(size_t)s3*64 + lane];
                            accx += u0.x*w0; accy += u0.y*w0;
                            accx += u1.x*w1; accy += u1.y*w1;
                            accx += u2.x*w2; accy += u2.y*w2;
                            accx += u3.x*w3; accy += u3.y*w3;
                        }
                        for (; j < m; ++j){
                            int   s = __shfl(s_l, j);
                            float w = __shfl(w_l, j);
                            float2 u = XF[(size_t)s*64 + lane];
                            accx += u.x*w; accy += u.y*w;
                        }
                    }
                    accx = elu_f(accx + loadf(Bl, lane*2,     0));
                    accy = elu_f(accy + loadf(Bl, lane*2 + 1, 0));
                    *(float2*)((float*)dout + (size_t)n*128 + lane*2) = make_float2(accx, accy);
                }
            }
        }
        gbar(&bar[6 + 2*l]);
    }

    // ---------- P13: MLP head (only Wm2/bm2 survive the reference's bug) ----------
    {
        float* ws_ = (float*)xs;
        for (int i = tid; i < 1280; i += 256) ws_[i] = loadf(Wm, i, isbf);
        __syncthreads();
        for (int idx = gid; idx < N*16; idx += GTHR){
            int row = idx >> 4;
            int c   = idx & 15;
            if (c < 10){
                float acc = 0.f;
                if (isbf){
                    const bf16* hr = (const bf16*)dout + (size_t)row*128;
                    #pragma unroll 8
                    for (int k = 0; k < 128; k++) acc += __bfloat162float(hr[k])*ws_[k*10 + c];
                } else {
                    const float* hr = (const float*)dout + (size_t)row*128;
                    #pragma unroll 8
                    for (int k = 0; k < 128; k++) acc += hr[k]*ws_[k*10 + c];
                }
                acc += loadf(bm, c, isbf);
                float r = elu_f(acc);
                if (isbf) ((bf16*)dout)[(size_t)N*128 + (size_t)row*10 + c] = __float2bfloat16(r);
                else      ((float*)dout)[(size_t)N*128 + (size_t)row*10 + c] = r;
            }
        }
    }
}

static inline char* alignup(char* p, size_t a){ return (char*)(((uintptr_t)p + a - 1) & ~(a - 1)); }

extern "C" void kernel_launch(void* const* d_in, const int* in_sizes, int n_in,
                              void* d_out, int out_size, void* d_ws, size_t ws_size,
                              hipStream_t stream){
    const void* x  = d_in[0];
    const int*  ei = (const int*)d_in[1];

    int N = in_sizes[0] / 128;
    int E = in_sizes[1] / 2;

    char* p = (char*)d_ws;
    int*   ctl      = (int*)p;                     p = alignup(p + 64*sizeof(int), 256);
    float* dinv     = (float*)p;                   p = alignup(p + (size_t)N*4, 256);
    int*   counts   = (int*)p;                     p = alignup(p + (size_t)N*4, 256);
    int*   offsets  = (int*)p;                     p = alignup(p + (size_t)N*4, 256);
    int*   cursor   = (int*)p;                     p = alignup(p + (size_t)N*4, 256);
    int*   partial  = (int*)p;                     p = alignup(p + 4096*4, 256);
    int*   blockoff = (int*)p;                     p = alignup(p + 4096*4, 256);
    bf16*  wt       = (bf16*)p;                    p = alignup(p + (size_t)4*16384*2, 256);
    int*   csr      = (int*)p;                     p = alignup(p + (size_t)E*4, 256);
    void*  xw       = (void*)p;                    p = alignup(p + (size_t)N*128*4, 256);

    (void)hipMemsetAsync(ctl, 0, 64*sizeof(int), stream);
    mega_kernel<<<GBLK, 256, 0, stream>>>(
        x, ei,
        d_in[2], d_in[4], d_in[6], d_in[8],
        d_in[3], d_in[5], d_in[7], d_in[9],
        d_in[12], d_in[13],
        ctl, dinv, counts, offsets, cursor, partial, blockoff, wt, csr, xw,
        d_out, N, E);
}